// Round 1
// baseline (486.271 us; speedup 1.0000x reference)
//
#include <hip/hip_runtime.h>
#include <math.h>

#define N_ENTITY 64368
#define N_REL 12
#define DIM 128
#define NB 8
#define N_ITEM 6924
#define NEDGE 1000000
#define BATCH 128
#define SEQL 32
#define ITEM_TILE 32

// ---------------------------------------------------------------------------
// Kernel 1: edge scatter.  Only edges with dst < N_ITEM matter (scores/pool
// only read nodes[:N_ITEM]).  One wave handles 64 edges' dst checks, ballots
// the kept ones (~10.8%), then the full wave processes each kept edge:
// msg = sum_b att[type,b] * basis[b,src,:], atomically added into aggr[dst,:].
// Each lane covers 2 of the 128 dims -> one 512B coalesced row read per plane.
// ---------------------------------------------------------------------------
__global__ __launch_bounds__(256) void edge_scatter_kernel(
    const int* __restrict__ e_src, const int* __restrict__ e_dst,
    const int* __restrict__ e_type, const float* __restrict__ basis,
    const float* __restrict__ att, float* __restrict__ aggr,
    float* __restrict__ deg)
{
    __shared__ float att_s[N_REL * NB];
    if (threadIdx.x < N_REL * NB) att_s[threadIdx.x] = att[threadIdx.x];
    __syncthreads();

    int gid  = blockIdx.x * 256 + threadIdx.x;
    int lane = threadIdx.x & 63;

    int d = 0, s = 0, t = 0;
    bool keep = false;
    if (gid < NEDGE) {
        d = e_dst[gid];
        keep = (d < N_ITEM);
        if (keep) { s = e_src[gid]; t = e_type[gid]; }
    }
    unsigned long long mask = __ballot(keep);
    while (mask) {
        int l = __ffsll((unsigned long long)mask) - 1;
        mask &= mask - 1;
        int dd = __shfl(d, l);
        int ss = __shfl(s, l);
        int tt = __shfl(t, l);

        const float* bp = basis + (size_t)ss * DIM + lane * 2;
        float accx = 0.f, accy = 0.f;
        #pragma unroll
        for (int b = 0; b < NB; ++b) {
            float a = att_s[tt * NB + b];
            float2 v = *reinterpret_cast<const float2*>(bp + (size_t)b * N_ENTITY * DIM);
            accx += a * v.x;
            accy += a * v.y;
        }
        float* outp = aggr + (size_t)dd * DIM + lane * 2;
        atomicAdd(outp,     accx);
        atomicAdd(outp + 1, accy);
        if (lane == 0) atomicAdd(deg + dd, 1.0f);
    }
}

// ---------------------------------------------------------------------------
// Kernel 2: nodes[n,:] = aggr[n,:]/max(deg[n],1) + root[n,:] + bias  (n < N_ITEM)
// ---------------------------------------------------------------------------
__global__ __launch_bounds__(256) void finalize_kernel(
    const float* __restrict__ aggr, const float* __restrict__ deg,
    const float* __restrict__ root, const float* __restrict__ bias,
    float* __restrict__ nodes)
{
    int idx = blockIdx.x * 256 + threadIdx.x;   // one float4 per thread
    if (idx >= N_ITEM * (DIM / 4)) return;
    int n  = idx >> 5;
    int kq = idx & 31;
    float inv = 1.0f / fmaxf(deg[n], 1.0f);
    float4 a  = reinterpret_cast<const float4*>(aggr)[idx];
    float4 r  = reinterpret_cast<const float4*>(root)[idx];   // root rows n<N_ITEM coincide
    float4 bs = reinterpret_cast<const float4*>(bias)[kq];
    float4 o;
    o.x = a.x * inv + r.x + bs.x;
    o.y = a.y * inv + r.y + bs.y;
    o.z = a.z * inv + r.z + bs.z;
    o.w = a.w * inv + r.w + bs.w;
    reinterpret_cast<float4*>(nodes)[idx] = o;
}

// ---------------------------------------------------------------------------
// Kernel 3: attention pool.  One block per batch row.
// h = nodes[seed_ids[b]] (32x128, LDS stride 132 to kill bank conflicts),
// e_l = tanh(h @ A) @ bvec, masked softmax over L, u = attn @ h.
// ---------------------------------------------------------------------------
__global__ __launch_bounds__(256) void pool_kernel(
    const float* __restrict__ nodes, const int* __restrict__ seed_ids,
    const int* __restrict__ seed_len, const float* __restrict__ attn_a,
    const float* __restrict__ attn_b, float* __restrict__ u)
{
    __shared__ float h[SEQL * 132];
    __shared__ float ev[SEQL];
    __shared__ float attw[SEQL];
    __shared__ int   seeds[SEQL];

    int b   = blockIdx.x;
    int tid = threadIdx.x;
    int len = seed_len[b];

    if (tid < SEQL) seeds[tid] = seed_ids[b * SEQL + tid];
    __syncthreads();

    for (int idx = tid; idx < SEQL * (DIM / 4); idx += 256) {
        int l  = idx >> 5;
        int kq = idx & 31;
        float4 v = reinterpret_cast<const float4*>(nodes)[(size_t)seeds[l] * 32 + kq];
        *reinterpret_cast<float4*>(h + l * 132 + kq * 4) = v;
    }
    __syncthreads();

    // e_l: 8 threads per l, each covers 16 output dims; k-outer keeps h in reg.
    {
        int l = tid >> 3;
        int j = tid & 7;
        float dot[16];
        #pragma unroll
        for (int i = 0; i < 16; ++i) dot[i] = 0.f;
        const float* hr = h + l * 132;
        for (int k = 0; k < DIM; ++k) {
            float hv = hr[k];
            const float4* ar = reinterpret_cast<const float4*>(attn_a + k * DIM + j * 16);
            float4 a0 = ar[0], a1 = ar[1], a2 = ar[2], a3 = ar[3];
            dot[0]  += hv * a0.x; dot[1]  += hv * a0.y; dot[2]  += hv * a0.z; dot[3]  += hv * a0.w;
            dot[4]  += hv * a1.x; dot[5]  += hv * a1.y; dot[6]  += hv * a1.z; dot[7]  += hv * a1.w;
            dot[8]  += hv * a2.x; dot[9]  += hv * a2.y; dot[10] += hv * a2.z; dot[11] += hv * a2.w;
            dot[12] += hv * a3.x; dot[13] += hv * a3.y; dot[14] += hv * a3.z; dot[15] += hv * a3.w;
        }
        float sum = 0.f;
        #pragma unroll
        for (int i = 0; i < 16; ++i) sum += tanhf(dot[i]) * attn_b[j * 16 + i];
        sum += __shfl_xor(sum, 1);
        sum += __shfl_xor(sum, 2);
        sum += __shfl_xor(sum, 4);
        if (j == 0) ev[l] = sum;
    }
    __syncthreads();

    if (tid < SEQL) {  // lanes 0..31 of wave 0
        float val = (tid < len) ? ev[tid] : -3.0e38f;
        float m = val;
        #pragma unroll
        for (int off = 16; off > 0; off >>= 1) m = fmaxf(m, __shfl_xor(m, off));
        float p = (tid < len) ? expf(val - m) : 0.f;
        float ssum = p;
        #pragma unroll
        for (int off = 16; off > 0; off >>= 1) ssum += __shfl_xor(ssum, off);
        attw[tid] = (len > 0) ? p / ssum : 0.f;   // len==0 -> u = 0 (matches where())
    }
    __syncthreads();

    if (tid < DIM) {
        float acc = 0.f;
        #pragma unroll
        for (int l = 0; l < SEQL; ++l) acc += attw[l] * h[l * 132 + tid];
        u[(size_t)b * DIM + tid] = acc;
    }
}

// ---------------------------------------------------------------------------
// Kernel 4: scores[b,i] = u[b,:] . nodes[i,:] + out_bias[i]
// Block: all 128 b x 32-item tile; u staged fully in LDS (64KB),
// item tile padded to stride 132.  Each thread: 8 b x 2 items.
// ---------------------------------------------------------------------------
__global__ __launch_bounds__(256) void score_kernel(
    const float* __restrict__ nodes, const float* __restrict__ u,
    const float* __restrict__ out_bias, float* __restrict__ out)
{
    __shared__ float us[BATCH * DIM];
    __shared__ float ns[ITEM_TILE * 132];
    int tid   = threadIdx.x;
    int item0 = blockIdx.x * ITEM_TILE;

    for (int idx = tid; idx < BATCH * (DIM / 4); idx += 256)
        reinterpret_cast<float4*>(us)[idx] = reinterpret_cast<const float4*>(u)[idx];

    for (int idx = tid; idx < ITEM_TILE * (DIM / 4); idx += 256) {
        int j  = idx >> 5;
        int kq = idx & 31;
        int item = item0 + j;
        float4 v = make_float4(0.f, 0.f, 0.f, 0.f);
        if (item < N_ITEM) v = reinterpret_cast<const float4*>(nodes)[(size_t)item * 32 + kq];
        *reinterpret_cast<float4*>(ns + j * 132 + kq * 4) = v;
    }
    __syncthreads();

    int jg = tid & 15;   // item pair index
    int bg = tid >> 4;   // b-group: b = bg*8 .. bg*8+7
    float acc0[8], acc1[8];
    #pragma unroll
    for (int i = 0; i < 8; ++i) { acc0[i] = 0.f; acc1[i] = 0.f; }
    const float* n0p = ns + (jg * 2 + 0) * 132;
    const float* n1p = ns + (jg * 2 + 1) * 132;
    for (int k = 0; k < DIM; k += 4) {
        float4 n0 = *reinterpret_cast<const float4*>(n0p + k);
        float4 n1 = *reinterpret_cast<const float4*>(n1p + k);
        #pragma unroll
        for (int bb = 0; bb < 8; ++bb) {
            float4 uv = *reinterpret_cast<const float4*>(us + (bg * 8 + bb) * DIM + k);
            acc0[bb] += uv.x * n0.x + uv.y * n0.y + uv.z * n0.z + uv.w * n0.w;
            acc1[bb] += uv.x * n1.x + uv.y * n1.y + uv.z * n1.z + uv.w * n1.w;
        }
    }
    #pragma unroll
    for (int bb = 0; bb < 8; ++bb) {
        int bi  = bg * 8 + bb;
        int it0 = item0 + jg * 2;
        if (it0     < N_ITEM) out[(size_t)bi * N_ITEM + it0]     = acc0[bb] + out_bias[it0];
        if (it0 + 1 < N_ITEM) out[(size_t)bi * N_ITEM + it0 + 1] = acc1[bb] + out_bias[it0 + 1];
    }
}

extern "C" void kernel_launch(void* const* d_in, const int* in_sizes, int n_in,
                              void* d_out, int out_size, void* d_ws, size_t ws_size,
                              hipStream_t stream)
{
    const int*   e_src     = (const int*)d_in[0];          // edge_idx[0]
    const int*   e_dst     = e_src + NEDGE;                // edge_idx[1]
    const int*   e_type    = (const int*)d_in[1];
    const int*   seed_ids  = (const int*)d_in[2];
    const int*   seed_len  = (const int*)d_in[3];
    // d_in[4] = labels (unused by reference)
    const float* basis     = (const float*)d_in[5];
    const float* att       = (const float*)d_in[6];
    const float* root      = (const float*)d_in[7];
    const float* rgcn_bias = (const float*)d_in[8];
    const float* attn_a    = (const float*)d_in[9];
    const float* attn_b    = (const float*)d_in[10];
    const float* out_bias  = (const float*)d_in[11];
    float*       out       = (float*)d_out;

    // workspace layout (~7.2 MB): aggr | deg | nodes | u
    float* aggr  = (float*)d_ws;
    float* deg   = aggr + (size_t)N_ITEM * DIM;
    float* nodes = deg + N_ITEM;
    float* u     = nodes + (size_t)N_ITEM * DIM;

    hipMemsetAsync(aggr, 0, ((size_t)N_ITEM * DIM + N_ITEM) * sizeof(float), stream);

    edge_scatter_kernel<<<(NEDGE + 255) / 256, 256, 0, stream>>>(
        e_src, e_dst, e_type, basis, att, aggr, deg);
    finalize_kernel<<<(N_ITEM * (DIM / 4) + 255) / 256, 256, 0, stream>>>(
        aggr, deg, root, rgcn_bias, nodes);
    pool_kernel<<<BATCH, 256, 0, stream>>>(
        nodes, seed_ids, seed_len, attn_a, attn_b, u);
    score_kernel<<<(N_ITEM + ITEM_TILE - 1) / ITEM_TILE, 256, 0, stream>>>(
        nodes, u, out_bias, out);
}

// Round 2
// 481.122 us; speedup vs baseline: 1.0107x; 1.0107x over previous
//
#include <hip/hip_runtime.h>
#include <math.h>

#define N_ENTITY 64368
#define N_REL 12
#define DIM 128
#define NB 8
#define N_ITEM 6924
#define NEDGE 1000000
#define BATCH 128
#define SEQL 32
#define ITEM_TILE 32

// ---------------------------------------------------------------------------
// Phase 1a: count kept edges (dst < N_ITEM) per dst.  Only ~10.8% of edges
// survive; int atomics into a 27 KB L2-resident counter array are cheap.
// ---------------------------------------------------------------------------
__global__ __launch_bounds__(256) void count_kernel(
    const int* __restrict__ e_dst, int* __restrict__ cnt)
{
    int gid = blockIdx.x * 256 + threadIdx.x;
    if (gid < NEDGE) {
        int d = e_dst[gid];
        if (d < N_ITEM) atomicAdd(&cnt[d], 1);
    }
}

// ---------------------------------------------------------------------------
// Phase 1b: exclusive prefix scan over cnt[N_ITEM] (single block, 256 thr,
// 28 elems/thread serial + Hillis-Steele over 256 partials).  Writes offs
// and a cursor copy for the fill phase.
// ---------------------------------------------------------------------------
#define SCAN_CHUNK 28
__global__ __launch_bounds__(256) void scan_kernel(
    const int* __restrict__ cnt, int* __restrict__ offs, int* __restrict__ cursor)
{
    __shared__ int part[256];
    int tid = threadIdx.x;
    int local[SCAN_CHUNK];
    int s = 0;
    #pragma unroll
    for (int i = 0; i < SCAN_CHUNK; ++i) {
        int idx = tid * SCAN_CHUNK + i;
        local[i] = s;
        s += (idx < N_ITEM) ? cnt[idx] : 0;
    }
    part[tid] = s;
    __syncthreads();
    for (int off = 1; off < 256; off <<= 1) {
        int v = (tid >= off) ? part[tid - off] : 0;
        __syncthreads();
        part[tid] += v;
        __syncthreads();
    }
    int base = (tid == 0) ? 0 : part[tid - 1];
    #pragma unroll
    for (int i = 0; i < SCAN_CHUNK; ++i) {
        int idx = tid * SCAN_CHUNK + i;
        if (idx < N_ITEM) { int o = base + local[i]; offs[idx] = o; cursor[idx] = o; }
    }
    if (tid == 255) offs[N_ITEM] = part[255];
}

// ---------------------------------------------------------------------------
// Phase 1c: scatter kept edges into dst buckets as packed src|type<<17
// (src < 2^17, type < 12).  Coalesced reads of src/type; scattered 4B writes.
// ---------------------------------------------------------------------------
__global__ __launch_bounds__(256) void fill_kernel(
    const int* __restrict__ e_src, const int* __restrict__ e_dst,
    const int* __restrict__ e_type, int* __restrict__ cursor,
    int* __restrict__ bucket)
{
    int gid = blockIdx.x * 256 + threadIdx.x;
    if (gid < NEDGE) {
        int d = e_dst[gid];
        if (d < N_ITEM) {
            int pos = atomicAdd(&cursor[d], 1);
            bucket[pos] = e_src[gid] | (e_type[gid] << 17);
        }
    }
}

// ---------------------------------------------------------------------------
// Phase 2: one wave per item row.  Wave loads its bucket's packed metadata
// (64 at a time, one coalesced transaction), then per edge gathers the 8
// basis planes (lane covers 2 dims -> 512B coalesced row read per plane)
// and accumulates in registers.  NO fp32 atomics.  Finalize (deg-normalize
// + root + bias) fused into the epilogue.
// ---------------------------------------------------------------------------
__global__ __launch_bounds__(256) void aggregate_kernel(
    const int* __restrict__ offs, const int* __restrict__ bucket,
    const float* __restrict__ basis, const float* __restrict__ att,
    const float* __restrict__ root, const float* __restrict__ bias,
    float* __restrict__ nodes)
{
    __shared__ float att_s[N_REL * NB];
    if (threadIdx.x < N_REL * NB) att_s[threadIdx.x] = att[threadIdx.x];
    __syncthreads();

    int wave = threadIdx.x >> 6;
    int lane = threadIdx.x & 63;
    int row  = blockIdx.x * 4 + wave;
    if (row >= N_ITEM) return;

    int o0 = offs[row], o1 = offs[row + 1];
    int n  = o1 - o0;

    float accx = 0.f, accy = 0.f;
    for (int base = 0; base < n; base += 64) {
        int m = n - base; if (m > 64) m = 64;
        int pk = 0;
        if (lane < m) pk = bucket[o0 + base + lane];
        for (int j = 0; j < m; ++j) {
            int p  = __shfl(pk, j);
            int ss = p & 0x1FFFF;
            int tt = p >> 17;
            const float* bp = basis + (size_t)ss * DIM + lane * 2;
            #pragma unroll
            for (int b = 0; b < NB; ++b) {
                float a = att_s[tt * NB + b];
                float2 v = *reinterpret_cast<const float2*>(bp + (size_t)b * (N_ENTITY * DIM));
                accx += a * v.x;
                accy += a * v.y;
            }
        }
    }
    float inv = 1.0f / fmaxf((float)n, 1.0f);
    float2 r  = *reinterpret_cast<const float2*>(root + (size_t)row * DIM + lane * 2);
    float2 bs = *reinterpret_cast<const float2*>(bias + lane * 2);
    float2 o;
    o.x = accx * inv + r.x + bs.x;
    o.y = accy * inv + r.y + bs.y;
    *reinterpret_cast<float2*>(nodes + (size_t)row * DIM + lane * 2) = o;
}

// ---------------------------------------------------------------------------
// Phase 3: attention pool.  One block per batch row.
// ---------------------------------------------------------------------------
__global__ __launch_bounds__(256) void pool_kernel(
    const float* __restrict__ nodes, const int* __restrict__ seed_ids,
    const int* __restrict__ seed_len, const float* __restrict__ attn_a,
    const float* __restrict__ attn_b, float* __restrict__ u)
{
    __shared__ float h[SEQL * 132];
    __shared__ float ev[SEQL];
    __shared__ float attw[SEQL];
    __shared__ int   seeds[SEQL];

    int b   = blockIdx.x;
    int tid = threadIdx.x;
    int len = seed_len[b];

    if (tid < SEQL) seeds[tid] = seed_ids[b * SEQL + tid];
    __syncthreads();

    for (int idx = tid; idx < SEQL * (DIM / 4); idx += 256) {
        int l  = idx >> 5;
        int kq = idx & 31;
        float4 v = reinterpret_cast<const float4*>(nodes)[(size_t)seeds[l] * 32 + kq];
        *reinterpret_cast<float4*>(h + l * 132 + kq * 4) = v;
    }
    __syncthreads();

    {
        int l = tid >> 3;
        int j = tid & 7;
        float dot[16];
        #pragma unroll
        for (int i = 0; i < 16; ++i) dot[i] = 0.f;
        const float* hr = h + l * 132;
        for (int k = 0; k < DIM; ++k) {
            float hv = hr[k];
            const float4* ar = reinterpret_cast<const float4*>(attn_a + k * DIM + j * 16);
            float4 a0 = ar[0], a1 = ar[1], a2 = ar[2], a3 = ar[3];
            dot[0]  += hv * a0.x; dot[1]  += hv * a0.y; dot[2]  += hv * a0.z; dot[3]  += hv * a0.w;
            dot[4]  += hv * a1.x; dot[5]  += hv * a1.y; dot[6]  += hv * a1.z; dot[7]  += hv * a1.w;
            dot[8]  += hv * a2.x; dot[9]  += hv * a2.y; dot[10] += hv * a2.z; dot[11] += hv * a2.w;
            dot[12] += hv * a3.x; dot[13] += hv * a3.y; dot[14] += hv * a3.z; dot[15] += hv * a3.w;
        }
        float sum = 0.f;
        #pragma unroll
        for (int i = 0; i < 16; ++i) sum += tanhf(dot[i]) * attn_b[j * 16 + i];
        sum += __shfl_xor(sum, 1);
        sum += __shfl_xor(sum, 2);
        sum += __shfl_xor(sum, 4);
        if (j == 0) ev[l] = sum;
    }
    __syncthreads();

    if (tid < SEQL) {
        float val = (tid < len) ? ev[tid] : -3.0e38f;
        float m = val;
        #pragma unroll
        for (int off = 16; off > 0; off >>= 1) m = fmaxf(m, __shfl_xor(m, off));
        float p = (tid < len) ? expf(val - m) : 0.f;
        float ssum = p;
        #pragma unroll
        for (int off = 16; off > 0; off >>= 1) ssum += __shfl_xor(ssum, off);
        attw[tid] = (len > 0) ? p / ssum : 0.f;
    }
    __syncthreads();

    if (tid < DIM) {
        float acc = 0.f;
        #pragma unroll
        for (int l = 0; l < SEQL; ++l) acc += attw[l] * h[l * 132 + tid];
        u[(size_t)b * DIM + tid] = acc;
    }
}

// ---------------------------------------------------------------------------
// Phase 4: scores[b,i] = u[b,:] . nodes[i,:] + out_bias[i]
// ---------------------------------------------------------------------------
__global__ __launch_bounds__(256) void score_kernel(
    const float* __restrict__ nodes, const float* __restrict__ u,
    const float* __restrict__ out_bias, float* __restrict__ out)
{
    __shared__ float us[BATCH * DIM];
    __shared__ float ns[ITEM_TILE * 132];
    int tid   = threadIdx.x;
    int item0 = blockIdx.x * ITEM_TILE;

    for (int idx = tid; idx < BATCH * (DIM / 4); idx += 256)
        reinterpret_cast<float4*>(us)[idx] = reinterpret_cast<const float4*>(u)[idx];

    for (int idx = tid; idx < ITEM_TILE * (DIM / 4); idx += 256) {
        int j  = idx >> 5;
        int kq = idx & 31;
        int item = item0 + j;
        float4 v = make_float4(0.f, 0.f, 0.f, 0.f);
        if (item < N_ITEM) v = reinterpret_cast<const float4*>(nodes)[(size_t)item * 32 + kq];
        *reinterpret_cast<float4*>(ns + j * 132 + kq * 4) = v;
    }
    __syncthreads();

    int jg = tid & 15;
    int bg = tid >> 4;
    float acc0[8], acc1[8];
    #pragma unroll
    for (int i = 0; i < 8; ++i) { acc0[i] = 0.f; acc1[i] = 0.f; }
    const float* n0p = ns + (jg * 2 + 0) * 132;
    const float* n1p = ns + (jg * 2 + 1) * 132;
    for (int k = 0; k < DIM; k += 4) {
        float4 n0 = *reinterpret_cast<const float4*>(n0p + k);
        float4 n1 = *reinterpret_cast<const float4*>(n1p + k);
        #pragma unroll
        for (int bb = 0; bb < 8; ++bb) {
            float4 uv = *reinterpret_cast<const float4*>(us + (bg * 8 + bb) * DIM + k);
            acc0[bb] += uv.x * n0.x + uv.y * n0.y + uv.z * n0.z + uv.w * n0.w;
            acc1[bb] += uv.x * n1.x + uv.y * n1.y + uv.z * n1.z + uv.w * n1.w;
        }
    }
    #pragma unroll
    for (int bb = 0; bb < 8; ++bb) {
        int bi  = bg * 8 + bb;
        int it0 = item0 + jg * 2;
        if (it0     < N_ITEM) out[(size_t)bi * N_ITEM + it0]     = acc0[bb] + out_bias[it0];
        if (it0 + 1 < N_ITEM) out[(size_t)bi * N_ITEM + it0 + 1] = acc1[bb] + out_bias[it0 + 1];
    }
}

extern "C" void kernel_launch(void* const* d_in, const int* in_sizes, int n_in,
                              void* d_out, int out_size, void* d_ws, size_t ws_size,
                              hipStream_t stream)
{
    const int*   e_src     = (const int*)d_in[0];          // edge_idx[0]
    const int*   e_dst     = e_src + NEDGE;                // edge_idx[1]
    const int*   e_type    = (const int*)d_in[1];
    const int*   seed_ids  = (const int*)d_in[2];
    const int*   seed_len  = (const int*)d_in[3];
    // d_in[4] = labels (unused by reference)
    const float* basis     = (const float*)d_in[5];
    const float* att       = (const float*)d_in[6];
    const float* root      = (const float*)d_in[7];
    const float* rgcn_bias = (const float*)d_in[8];
    const float* attn_a    = (const float*)d_in[9];
    const float* attn_b    = (const float*)d_in[10];
    const float* out_bias  = (const float*)d_in[11];
    float*       out       = (float*)d_out;

    // workspace layout: cnt | offs | cursor | bucket | nodes | u  (~7.7 MB)
    int*   cnt    = (int*)d_ws;
    int*   offs   = cnt + 6928;
    int*   cursor = offs + 6928;
    int*   bucket = cursor + 6928;
    float* nodes  = (float*)(bucket + NEDGE);
    float* u      = nodes + (size_t)N_ITEM * DIM;

    hipMemsetAsync(cnt, 0, 6928 * sizeof(int), stream);

    count_kernel<<<(NEDGE + 255) / 256, 256, 0, stream>>>(e_dst, cnt);
    scan_kernel<<<1, 256, 0, stream>>>(cnt, offs, cursor);
    fill_kernel<<<(NEDGE + 255) / 256, 256, 0, stream>>>(e_src, e_dst, e_type, cursor, bucket);
    aggregate_kernel<<<(N_ITEM + 3) / 4, 256, 0, stream>>>(
        offs, bucket, basis, att, root, rgcn_bias, nodes);
    pool_kernel<<<BATCH, 256, 0, stream>>>(
        nodes, seed_ids, seed_len, attn_a, attn_b, u);
    score_kernel<<<(N_ITEM + ITEM_TILE - 1) / ITEM_TILE, 256, 0, stream>>>(
        nodes, u, out_bias, out);
}